// Round 5
// baseline (340.596 us; speedup 1.0000x reference)
//
#include <hip/hip_runtime.h>

#define N_NODES 50000
#define N_EDGES 1600000
#define HEADS 4
#define DPH 16
#define F_IN 128
#define HD 64   // HEADS * DPH
#define NCHAIN 4

__device__ inline unsigned pack_bf16(float k, float v) {
    unsigned uk = __float_as_uint(k), uv = __float_as_uint(v);
    uk = (uk + 0x7FFFu + ((uk >> 16) & 1u)) >> 16;   // RNE to bf16
    uv = (uv + 0x7FFFu + ((uv >> 16) & 1u)) >> 16;
    return (uv << 16) | uk;
}

// ---------------------------------------------------------------------------
// Kernel 1: fused QKV projection. Q stays f32; K,V are packed to one
// interleaved bf16 word per (node,col) so the gather phase reads one line.
// ---------------------------------------------------------------------------
__global__ void qkv_proj(const float* __restrict__ x,
                         const float* __restrict__ Wq,
                         const float* __restrict__ Wk,
                         const float* __restrict__ Wv,
                         float* __restrict__ Q,
                         unsigned* __restrict__ KV) {
    __shared__ float xs[8][F_IN];
    __shared__ float kcol[8][64];
    __shared__ float vcol[8][64];
    const int node0 = blockIdx.x * 8;
    const int tid = threadIdx.x;

    for (int i = tid; i < 8 * F_IN; i += 192) {
        const int n = node0 + (i >> 7);
        xs[i >> 7][i & 127] = (n < N_NODES) ? x[(long)n * F_IN + (i & 127)] : 0.f;
    }
    __syncthreads();

    const int m = tid / 64;       // 0=Q, 1=K, 2=V
    const int col = tid & 63;
    const float* W = (m == 0) ? Wq : (m == 1) ? Wk : Wv;

    float acc[8] = {0.f, 0.f, 0.f, 0.f, 0.f, 0.f, 0.f, 0.f};
    for (int k = 0; k < F_IN; k += 4) {
        const float w0 = W[(k + 0) * HD + col];
        const float w1 = W[(k + 1) * HD + col];
        const float w2 = W[(k + 2) * HD + col];
        const float w3 = W[(k + 3) * HD + col];
        #pragma unroll
        for (int i = 0; i < 8; ++i) {
            const float4 xv = *(const float4*)&xs[i][k];
            acc[i] += xv.x * w0 + xv.y * w1 + xv.z * w2 + xv.w * w3;
        }
    }

    if (m == 0) {
        #pragma unroll
        for (int i = 0; i < 8; ++i) {
            const int n = node0 + i;
            if (n < N_NODES) Q[n * HD + col] = acc[i];
        }
    } else if (m == 1) {
        #pragma unroll
        for (int i = 0; i < 8; ++i) kcol[i][col] = acc[i];
    } else {
        #pragma unroll
        for (int i = 0; i < 8; ++i) vcol[i][col] = acc[i];
    }
    __syncthreads();
    if (m == 1) {
        #pragma unroll
        for (int i = 0; i < 8; ++i) {
            const int n = node0 + i;
            if (n < N_NODES) KV[n * HD + col] = pack_bf16(kcol[i][col], vcol[i][col]);
        }
    }
}

// ---------------------------------------------------------------------------
// Kernel 2: per-dst linked lists, NCHAIN interleaved chains per node.
// List cell elink[e] = {src[e], next}; 8B cell => one line per hop.
// ---------------------------------------------------------------------------
__global__ void build_links(const int* __restrict__ src,
                            const int* __restrict__ dst,
                            int* __restrict__ head,
                            int2* __restrict__ elink) {
    for (int i = blockIdx.x * blockDim.x + threadIdx.x; i < N_EDGES;
         i += gridDim.x * blockDim.x) {
        const int d = dst[i];
        const int nx = atomicExch(&head[d * NCHAIN + (i & (NCHAIN - 1))], i);
        elink[i] = make_int2(src[i], nx);
    }
}

// ---------------------------------------------------------------------------
// Kernel 3: pull gather, one wave per dst node, 4 concurrent chain walks.
// lane = h*16 + d; bf16 KV unpacked in-register.
// Loop guard uses AND: -1 is all-ones, so the AND is -1 iff ALL chains done.
// (Round-4 bug: OR exits as soon as ANY chain is done -> dropped edges.)
// ---------------------------------------------------------------------------
__global__ void node_gather(const int* __restrict__ head,
                            const int2* __restrict__ elink,
                            const float* __restrict__ Q,
                            const unsigned* __restrict__ KV,
                            float* __restrict__ out) {
    const int n = blockIdx.x * 4 + (threadIdx.x >> 6);
    if (n >= N_NODES) return;
    const int lane = threadIdx.x & 63;
    const float q = Q[n * HD + lane];

    int e0 = head[n * NCHAIN + 0];
    int e1 = head[n * NCHAIN + 1];
    int e2 = head[n * NCHAIN + 2];
    int e3 = head[n * NCHAIN + 3];

    float acc = 0.f, zacc = 0.f;

    while ((e0 & e1 & e2 & e3) != -1) {
        #define STEP(E)                                                       \
        if (E >= 0) {                                                         \
            const int2 l = elink[E];                                          \
            const unsigned kv = KV[l.x * HD + lane];                          \
            const float k = __uint_as_float(kv << 16);                        \
            const float v = __uint_as_float(kv & 0xFFFF0000u);                \
            float p = q * k;                                                  \
            p += __shfl_xor(p, 1, 16);                                        \
            p += __shfl_xor(p, 2, 16);                                        \
            p += __shfl_xor(p, 4, 16);                                        \
            p += __shfl_xor(p, 8, 16);                                        \
            const float sc = __expf(fminf(fmaxf(p * 0.25f, -5.f), 5.f));      \
            acc = fmaf(sc, v, acc);                                           \
            zacc += sc;                                                       \
            E = l.y;                                                          \
        }
        STEP(e0)
        STEP(e1)
        STEP(e2)
        STEP(e3)
        #undef STEP
    }
    out[n * HD + lane] = acc / (zacc + 1e-6f);
}

extern "C" void kernel_launch(void* const* d_in, const int* in_sizes, int n_in,
                              void* d_out, int out_size, void* d_ws, size_t ws_size,
                              hipStream_t stream) {
    const float* x   = (const float*)d_in[0];
    const int*   src = (const int*)d_in[1];
    const int*   dst = (const int*)d_in[2];
    const float* Wq  = (const float*)d_in[3];
    const float* Wk  = (const float*)d_in[4];
    const float* Wv  = (const float*)d_in[5];
    float* out = (float*)d_out;

    float*    Q     = (float*)d_ws;
    unsigned* KV    = (unsigned*)(Q + (size_t)N_NODES * HD);
    int*      head  = (int*)(KV + (size_t)N_NODES * HD);
    int2*     elink = (int2*)(head + (size_t)N_NODES * NCHAIN);

    hipMemsetAsync(head, 0xFF, (size_t)N_NODES * NCHAIN * sizeof(int), stream);

    qkv_proj<<<(N_NODES + 7) / 8, 192, 0, stream>>>(x, Wq, Wk, Wv, Q, KV);
    build_links<<<2048, 256, 0, stream>>>(src, dst, head, elink);
    node_gather<<<(N_NODES + 3) / 4, 256, 0, stream>>>(head, elink, Q, KV, out);
}